// Round 2
// baseline (386.525 us; speedup 1.0000x reference)
//
#include <hip/hip_runtime.h>
#include <hip/hip_bf16.h>
#include <stdint.h>

// Problem constants
#define L_DIM 1024
#define S_DIM 1024
#define N_DIM 8
#define E_DIM 1024
#define H_DIM 16
#define HD    64
#define BH    (N_DIM*H_DIM)    // 128 batch-heads
#define M_ROWS (L_DIM*N_DIM)   // 8192 rows for projection GEMMs

typedef __bf16 bf16x8 __attribute__((ext_vector_type(8)));
typedef float  f32x4  __attribute__((ext_vector_type(4)));
typedef _Float16 f16;
typedef _Float16 f16x8 __attribute__((ext_vector_type(8)));
typedef unsigned short u16;
typedef unsigned short u16x8 __attribute__((ext_vector_type(8)));

// round-to-nearest-even f32 -> bf16 (finite inputs only)
__device__ inline u16 f2bf(float x){
  unsigned int u = __float_as_uint(x);
  u = (u + 0x7FFFu + ((u >> 16) & 1u)) >> 16;
  return (u16)u;
}

// ---------------------------------------------------------------------------
// Kernel 0: convert query, key, Wq (x0.125 folded), Wk to bf16 (vectorized x8)
// ---------------------------------------------------------------------------
__global__ __launch_bounds__(256) void convert_kernel(
    const float* __restrict__ query, const float* __restrict__ key,
    const float* __restrict__ w,
    u16* __restrict__ qbf, u16* __restrict__ kbf,
    u16* __restrict__ wq, u16* __restrict__ wk)
{
  const int QN = M_ROWS*E_DIM;   // 8388608
  const int WN = E_DIM*E_DIM;    // 1048576
  const int total8 = (2*QN + 2*WN)/8;
  int stride = gridDim.x*blockDim.x;
  for (int g = blockIdx.x*blockDim.x + threadIdx.x; g < total8; g += stride) {
    int base = g*8;
    const float* src; u16* dst; float scale = 1.0f;
    if (base < QN)           { src = query + base;      dst = qbf + base; }
    else if (base < 2*QN)    { src = key + (base-QN);   dst = kbf + (base-QN); }
    else if (base < 2*QN+WN) { src = w + (base-2*QN);   dst = wq + (base-2*QN); scale = 0.125f; }
    else                     { src = w + (base-2*QN);   dst = wk + (base-2*QN-WN); }
    float4 v0 = *(const float4*)(src);
    float4 v1 = *(const float4*)(src+4);
    u16x8 o;
    o[0]=f2bf(v0.x*scale); o[1]=f2bf(v0.y*scale); o[2]=f2bf(v0.z*scale); o[3]=f2bf(v0.w*scale);
    o[4]=f2bf(v1.x*scale); o[5]=f2bf(v1.y*scale); o[6]=f2bf(v1.z*scale); o[7]=f2bf(v1.w*scale);
    *(u16x8*)dst = o;
  }
}

// ---------------------------------------------------------------------------
// Kernel 1/2: projection GEMM, C = A @ W^T + bscale*bias, bf16 in/out, f32 acc
// m97 structure: 128x128 tile, BK=32, 4 waves (2x2), global_load_lds width 16.
// ---------------------------------------------------------------------------
__global__ __launch_bounds__(256) void proj_gemm(
    const u16* __restrict__ A, const u16* __restrict__ W,
    const float* __restrict__ bias, float bscale,
    u16* __restrict__ C)
{
  __shared__ __align__(16) u16 As[128*32];
  __shared__ __align__(16) u16 Bs[128*32];
  const int t = threadIdx.x;
  const int lane = t & 63;
  const int w = t >> 6;
  const int wr = w >> 1, wc = w & 1;
  const int rowTile = blockIdx.x * 128;
  const int colTile = blockIdx.y * 128;

  f32x4 acc[4][4];
  #pragma unroll
  for (int m=0;m<4;m++)
    #pragma unroll
    for (int n=0;n<4;n++) acc[m][n] = (f32x4){0.f,0.f,0.f,0.f};

  uint32_t asBase = (uint32_t)(uintptr_t)&As[0];
  uint32_t bsBase = (uint32_t)(uintptr_t)&Bs[0];
  const char* Ab = (const char*)A;
  const char* Wb = (const char*)W;

  for (int kt = 0; kt < 32; ++kt) {
    __syncthreads();
    #pragma unroll
    for (int issue = 0; issue < 2; ++issue) {
      int o = issue*4096 + t*16;
      int row  = o >> 6;
      int colb = o & 63;
      const char* ga = Ab + (size_t)(rowTile + row)*2048 + kt*64 + colb;
      const char* gb = Wb + (size_t)(colTile + row)*2048 + kt*64 + colb;
      uint32_t la = asBase + issue*4096 + (w<<10);
      uint32_t lb = bsBase + issue*4096 + (w<<10);
      __builtin_amdgcn_global_load_lds(
          (const __attribute__((address_space(1))) void*)(uintptr_t)ga,
          (__attribute__((address_space(3))) void*)(uintptr_t)la, 16, 0, 0);
      __builtin_amdgcn_global_load_lds(
          (const __attribute__((address_space(1))) void*)(uintptr_t)gb,
          (__attribute__((address_space(3))) void*)(uintptr_t)lb, 16, 0, 0);
    }
    __syncthreads();

    bf16x8 af[4], bfr[4];
    int krow = (lane >> 4) * 16;
    #pragma unroll
    for (int m=0;m<4;m++) {
      int r = wr*64 + m*16 + (lane&15);
      af[m] = *(const bf16x8*)((const char*)As + r*64 + krow);
    }
    #pragma unroll
    for (int n=0;n<4;n++) {
      int r = wc*64 + n*16 + (lane&15);
      bfr[n] = *(const bf16x8*)((const char*)Bs + r*64 + krow);
    }
    #pragma unroll
    for (int m=0;m<4;m++)
      #pragma unroll
      for (int n=0;n<4;n++)
        acc[m][n] = __builtin_amdgcn_mfma_f32_16x16x32_bf16(af[m], bfr[n], acc[m][n], 0,0,0);
  }

  #pragma unroll
  for (int n=0;n<4;n++) {
    int gcol = colTile + wc*64 + n*16 + (lane&15);
    float bv = bias[gcol]*bscale;
    #pragma unroll
    for (int m=0;m<4;m++) {
      int grow0 = rowTile + wr*64 + m*16 + ((lane>>4)<<2);
      #pragma unroll
      for (int r=0;r<4;r++)
        C[(size_t)(grow0+r)*1024 + gcol] = f2bf(acc[m][n][r] + bv);
    }
  }
}

// ---------------------------------------------------------------------------
// Kernel 3: fused QK^T + attn_bias + softmax.
// Block = (16 q-rows) x (one batch-head). 4 waves; each wave computes 16 of the
// 64 s-tiles (16x16x32 MFMA x2 over hd=64). Scores staged in LDS as f16
// (32 KB -> 5 blocks/CU vs 2 at f32), XOR-swizzled (byte ^= (row&7)<<4) to
// break the 2048B row-stride bank degeneracy. Softmax phase: wave-per-row,
// nontemporal coalesced bias read + out write (streaming, no L2 pollution).
// ---------------------------------------------------------------------------
__global__ __launch_bounds__(256) void attn_softmax(
    const u16* __restrict__ Qb, const u16* __restrict__ Kb,
    const float* __restrict__ bias, float* __restrict__ out)
{
  __shared__ __align__(16) char scb[16*2048];   // 32 KB f16 scores, swizzled
  const int t = threadIdx.x;
  const int lane = t & 63;
  const int w = t >> 6;
  const int ltile = blockIdx.x;     // 64 tiles of 16 q-rows
  const int b = blockIdx.y;         // 128 batch-heads
  const int n = b >> 4, h = b & 15;

  // A-frags: Q rows (this block's 16 rows), k = d in [0,64)
  int l_row = ltile*16 + (lane & 15);
  size_t qoff = ((size_t)(l_row*8 + n))*1024 + h*64 + ((lane>>4)*8);
  bf16x8 a0 = *(const bf16x8*)(Qb + qoff);
  bf16x8 a1 = *(const bf16x8*)(Qb + qoff + 32);

  const int rowBase = (lane>>4)*4;

  for (int st = w; st < 64; st += 4) {
    int s_row = st*16 + (lane & 15);
    size_t koff = ((size_t)(s_row*8 + n))*1024 + h*64 + ((lane>>4)*8);
    bf16x8 b0 = *(const bf16x8*)(Kb + koff);
    bf16x8 b1 = *(const bf16x8*)(Kb + koff + 32);
    f32x4 acc = {0.f,0.f,0.f,0.f};
    acc = __builtin_amdgcn_mfma_f32_16x16x32_bf16(a0, b0, acc, 0,0,0);
    acc = __builtin_amdgcn_mfma_f32_16x16x32_bf16(a1, b1, acc, 0,0,0);
    int scol = st*16 + (lane & 15);
    #pragma unroll
    for (int r=0;r<4;r++) {
      int row = rowBase + r;
      int byte = (row*2048 + scol*2) ^ ((row&7)<<4);
      *(f16*)(scb + byte) = (f16)acc[r];
    }
  }
  __syncthreads();

  #pragma unroll
  for (int rr=0;rr<4;rr++) {
    int row = rr*4 + w;                       // wave w owns rows {w, w+4, w+8, w+12}
    int l_glob = ltile*16 + row;
    const float* brow = bias + ((size_t)b*1024 + l_glob)*1024;
    float*       orow = out  + ((size_t)b*1024 + l_glob)*1024;
    const int swz = (row&7)<<4;
    float v[16];
    float mx = -1e30f;
    #pragma unroll
    for (int it=0; it<2; ++it) {
      int cb = it*1024 + lane*16;                 // logical byte offset in row
      f16x8 s8 = *(const f16x8*)(scb + ((row*2048 + cb) ^ swz));
      int col = it*512 + lane*8;
      f32x4 b4a = __builtin_nontemporal_load((const f32x4*)(brow + col));
      f32x4 b4b = __builtin_nontemporal_load((const f32x4*)(brow + col + 4));
      #pragma unroll
      for (int j=0;j<4;j++) v[it*8+j]   = (float)s8[j]   + b4a[j];
      #pragma unroll
      for (int j=0;j<4;j++) v[it*8+4+j] = (float)s8[4+j] + b4b[j];
    }
    #pragma unroll
    for (int j=0;j<16;j++) mx = fmaxf(mx, v[j]);
    #pragma unroll
    for (int off=32; off>0; off>>=1) mx = fmaxf(mx, __shfl_xor(mx, off, 64));
    float sum = 0.f;
    #pragma unroll
    for (int j=0;j<16;j++) { v[j] = __expf(v[j]-mx); sum += v[j]; }
    #pragma unroll
    for (int off=32; off>0; off>>=1) sum += __shfl_xor(sum, off, 64);
    float inv = 1.0f / sum;
    #pragma unroll
    for (int it=0; it<2; ++it) {
      int col = it*512 + lane*8;
      f32x4 o4a = { v[it*8+0]*inv, v[it*8+1]*inv, v[it*8+2]*inv, v[it*8+3]*inv };
      f32x4 o4b = { v[it*8+4]*inv, v[it*8+5]*inv, v[it*8+6]*inv, v[it*8+7]*inv };
      __builtin_nontemporal_store(o4a, (f32x4*)(orow + col));
      __builtin_nontemporal_store(o4b, (f32x4*)(orow + col + 4));
    }
  }
}

// ---------------------------------------------------------------------------
// Workspace layout (68 MB total):
//   qbf 16 MB | kbf 16 MB | wq 2 MB | wk 2 MB | Qp 16 MB | Kp 16 MB
// ---------------------------------------------------------------------------
extern "C" void kernel_launch(void* const* d_in, const int* in_sizes, int n_in,
                              void* d_out, int out_size, void* d_ws, size_t ws_size,
                              hipStream_t stream) {
  const float* query = (const float*)d_in[0];
  const float* key   = (const float*)d_in[1];
  const float* w     = (const float*)d_in[2];
  const float* bias  = (const float*)d_in[3];
  const float* abias = (const float*)d_in[4];
  float* out = (float*)d_out;

  char* ws = (char*)d_ws;
  const size_t QKB = (size_t)M_ROWS*E_DIM*2;  // 16 MB
  const size_t WB  = (size_t)E_DIM*E_DIM*2;   // 2 MB
  u16* qbf = (u16*)ws;  ws += QKB;
  u16* kbf = (u16*)ws;  ws += QKB;
  u16* wq  = (u16*)ws;  ws += WB;
  u16* wk  = (u16*)ws;  ws += WB;
  u16* Qp  = (u16*)ws;  ws += QKB;
  u16* Kp  = (u16*)ws;  ws += QKB;

  hipLaunchKernelGGL(convert_kernel, dim3(2048), dim3(256), 0, stream,
                     query, key, w, qbf, kbf, wq, wk);
  hipLaunchKernelGGL(proj_gemm, dim3(64, 8), dim3(256), 0, stream,
                     qbf, wq, bias, 0.125f, Qp);
  hipLaunchKernelGGL(proj_gemm, dim3(64, 8), dim3(256), 0, stream,
                     kbf, wk, bias + 1024, 1.0f, Kp);
  hipLaunchKernelGGL(attn_softmax, dim3(64, 128), dim3(256), 0, stream,
                     Qp, Kp, abias, out);
}

// Round 3
// 322.325 us; speedup vs baseline: 1.1992x; 1.1992x over previous
//
#include <hip/hip_runtime.h>
#include <hip/hip_bf16.h>
#include <stdint.h>

// Problem constants
#define L_DIM 1024
#define S_DIM 1024
#define N_DIM 8
#define E_DIM 1024
#define H_DIM 16
#define HD    64
#define BH    (N_DIM*H_DIM)    // 128 batch-heads
#define M_ROWS (L_DIM*N_DIM)   // 8192 rows for projection GEMMs

#define AS1 __attribute__((address_space(1)))
#define AS3 __attribute__((address_space(3)))

typedef __bf16 bf16x8 __attribute__((ext_vector_type(8)));
typedef float  f32x4  __attribute__((ext_vector_type(4)));
typedef _Float16 f16;
typedef _Float16 f16x8 __attribute__((ext_vector_type(8)));
typedef unsigned short u16;
typedef unsigned short u16x8 __attribute__((ext_vector_type(8)));

// round-to-nearest-even f32 -> bf16 (finite inputs only)
__device__ inline u16 f2bf(float x){
  unsigned int u = __float_as_uint(x);
  u = (u + 0x7FFFu + ((u >> 16) & 1u)) >> 16;
  return (u16)u;
}

// ---------------------------------------------------------------------------
// Kernel 0: convert query, key, Wq (x0.125 folded), Wk to bf16 (vectorized x8)
// ---------------------------------------------------------------------------
__global__ __launch_bounds__(256) void convert_kernel(
    const float* __restrict__ query, const float* __restrict__ key,
    const float* __restrict__ w,
    u16* __restrict__ qbf, u16* __restrict__ kbf,
    u16* __restrict__ wq, u16* __restrict__ wk)
{
  const int QN = M_ROWS*E_DIM;   // 8388608
  const int WN = E_DIM*E_DIM;    // 1048576
  const int total8 = (2*QN + 2*WN)/8;
  int stride = gridDim.x*blockDim.x;
  for (int g = blockIdx.x*blockDim.x + threadIdx.x; g < total8; g += stride) {
    int base = g*8;
    const float* src; u16* dst; float scale = 1.0f;
    if (base < QN)           { src = query + base;      dst = qbf + base; }
    else if (base < 2*QN)    { src = key + (base-QN);   dst = kbf + (base-QN); }
    else if (base < 2*QN+WN) { src = w + (base-2*QN);   dst = wq + (base-2*QN); scale = 0.125f; }
    else                     { src = w + (base-2*QN);   dst = wk + (base-2*QN-WN); }
    float4 v0 = *(const float4*)(src);
    float4 v1 = *(const float4*)(src+4);
    u16x8 o;
    o[0]=f2bf(v0.x*scale); o[1]=f2bf(v0.y*scale); o[2]=f2bf(v0.z*scale); o[3]=f2bf(v0.w*scale);
    o[4]=f2bf(v1.x*scale); o[5]=f2bf(v1.y*scale); o[6]=f2bf(v1.z*scale); o[7]=f2bf(v1.w*scale);
    *(u16x8*)dst = o;
  }
}

// ---------------------------------------------------------------------------
// Kernel 1/2: projection GEMM, C = A @ W^T + bscale*bias, bf16 in, f32 acc.
// Output written HEAD-MAJOR: C[(n*16+h)][l_or_s][d], so each head's slice is
// a contiguous 128 KB (coalesced staging in the attn kernel).
// ---------------------------------------------------------------------------
__global__ __launch_bounds__(256) void proj_gemm(
    const u16* __restrict__ A, const u16* __restrict__ W,
    const float* __restrict__ bias, float bscale,
    u16* __restrict__ C)
{
  __shared__ __align__(16) u16 As[128*32];
  __shared__ __align__(16) u16 Bs[128*32];
  const int t = threadIdx.x;
  const int lane = t & 63;
  const int w = t >> 6;
  const int wr = w >> 1, wc = w & 1;
  const int rowTile = blockIdx.x * 128;
  const int colTile = blockIdx.y * 128;

  f32x4 acc[4][4];
  #pragma unroll
  for (int m=0;m<4;m++)
    #pragma unroll
    for (int n=0;n<4;n++) acc[m][n] = (f32x4){0.f,0.f,0.f,0.f};

  uint32_t asBase = (uint32_t)(uintptr_t)&As[0];
  uint32_t bsBase = (uint32_t)(uintptr_t)&Bs[0];
  const char* Ab = (const char*)A;
  const char* Wb = (const char*)W;

  for (int kt = 0; kt < 32; ++kt) {
    __syncthreads();
    #pragma unroll
    for (int issue = 0; issue < 2; ++issue) {
      int o = issue*4096 + t*16;
      int row  = o >> 6;
      int colb = o & 63;
      const char* ga = Ab + (size_t)(rowTile + row)*2048 + kt*64 + colb;
      const char* gb = Wb + (size_t)(colTile + row)*2048 + kt*64 + colb;
      uint32_t la = asBase + issue*4096 + (w<<10);
      uint32_t lb = bsBase + issue*4096 + (w<<10);
      __builtin_amdgcn_global_load_lds(
          (const AS1 void*)(uintptr_t)ga, (AS3 void*)(uintptr_t)la, 16, 0, 0);
      __builtin_amdgcn_global_load_lds(
          (const AS1 void*)(uintptr_t)gb, (AS3 void*)(uintptr_t)lb, 16, 0, 0);
    }
    __syncthreads();

    bf16x8 af[4], bfr[4];
    int krow = (lane >> 4) * 16;
    #pragma unroll
    for (int m=0;m<4;m++) {
      int r = wr*64 + m*16 + (lane&15);
      af[m] = *(const bf16x8*)((const char*)As + r*64 + krow);
    }
    #pragma unroll
    for (int n=0;n<4;n++) {
      int r = wc*64 + n*16 + (lane&15);
      bfr[n] = *(const bf16x8*)((const char*)Bs + r*64 + krow);
    }
    #pragma unroll
    for (int m=0;m<4;m++)
      #pragma unroll
      for (int n=0;n<4;n++)
        acc[m][n] = __builtin_amdgcn_mfma_f32_16x16x32_bf16(af[m], bfr[n], acc[m][n], 0,0,0);
  }

  // epilogue -> head-major [n*16+h][l][d]; A row = l*8+n, col = h*64+d
  #pragma unroll
  for (int n2=0;n2<4;n2++) {
    int gcol = colTile + wc*64 + n2*16 + (lane&15);
    int h = gcol >> 6, d = gcol & 63;
    float bv = bias[gcol]*bscale;
    #pragma unroll
    for (int m=0;m<4;m++) {
      int grow0 = rowTile + wr*64 + m*16 + ((lane>>4)<<2);
      #pragma unroll
      for (int r=0;r<4;r++) {
        int grow = grow0 + r;
        int l = grow >> 3, nn = grow & 7;
        C[((size_t)(nn*16 + h)*1024 + l)*64 + d] = f2bf(acc[m][n2][r] + bv);
      }
    }
  }
}

// ---------------------------------------------------------------------------
// Kernel 3: fused QK^T + attn_bias + softmax.
// Block = (16 q-rows) x (one batch-head), 4 waves.
// Phase 1: K slice staged through 8 KB LDS chunks via coalesced
//   global_load_lds (linear dest + inverse-XOR-swizzled source, rule #21);
//   fragment ds_reads apply the same swizzle -> 2-way (free) bank access.
//   Wave w computes s-tile g*4+w per chunk (2 MFMA over hd=64), scores -> f16
//   LDS (32 KB, swizzled).
// Phase 2: wave-per-row softmax, coalesced f32x4 bias read + out write.
// ---------------------------------------------------------------------------
__global__ __launch_bounds__(256) void attn_softmax(
    const u16* __restrict__ Qh, const u16* __restrict__ Kh,
    const float* __restrict__ bias, float* __restrict__ out)
{
  __shared__ __align__(16) char scb[16*2048];    // 32 KB f16 scores, swizzled
  __shared__ __align__(16) char kbuf[8192];      // 64 s-rows x 64 d, swizzled
  const int t = threadIdx.x;
  const int lane = t & 63;
  const int w = t >> 6;
  const int ltile = blockIdx.x;     // 64 tiles of 16 q-rows
  const int b = blockIdx.y;         // 128 batch-heads

  const char* Kb = (const char*)(Kh + (size_t)b*1024*64);               // 128 KB
  const u16*  Qb = Qh + (size_t)b*1024*64 + (size_t)ltile*16*64;        // 2 KB

  // A-frags: q-row = lane&15 (row stride 128 B), d = (lane>>4)*8
  int qoff = (lane&15)*64 + (lane>>4)*8;
  bf16x8 a0 = *(const bf16x8*)(Qb + qoff);
  bf16x8 a1 = *(const bf16x8*)(Qb + qoff + 32);

  const int rowBase = (lane>>4)*4;
  uint32_t kbase = (uint32_t)(uintptr_t)&kbuf[0];

  for (int g = 0; g < 16; ++g) {
    __syncthreads();   // previous chunk's readers done before overwrite
    #pragma unroll
    for (int rd = 0; rd < 2; ++rd) {
      int o = rd*4096 + t*16;                    // linear LDS byte offset
      int src = o ^ (((o>>7)&7)<<4);             // inverse swizzle (involution)
      __builtin_amdgcn_global_load_lds(
          (const AS1 void*)(uintptr_t)(Kb + (size_t)g*8192 + src),
          (AS3 void*)(uintptr_t)(kbase + rd*4096 + (w<<10)), 16, 0, 0);
    }
    __syncthreads();   // staging visible (compiler drains vmcnt before barrier)

    // wave w: s-tile st = g*4+w, local rows r = w*16 + (lane&15)
    int r = w*16 + (lane&15);
    int byte0 = r*128 + ((lane>>4)*16);
    int swzk = (r&7)<<4;
    bf16x8 b0 = *(const bf16x8*)(kbuf + ((byte0      ) ^ swzk));
    bf16x8 b1 = *(const bf16x8*)(kbuf + ((byte0 + 64 ) ^ swzk));
    f32x4 acc = {0.f,0.f,0.f,0.f};
    acc = __builtin_amdgcn_mfma_f32_16x16x32_bf16(a0, b0, acc, 0,0,0);
    acc = __builtin_amdgcn_mfma_f32_16x16x32_bf16(a1, b1, acc, 0,0,0);

    int scol = g*64 + w*16 + (lane & 15);        // global s index
    #pragma unroll
    for (int rr=0;rr<4;rr++) {
      int row = rowBase + rr;
      int byte = (row*2048 + scol*2) ^ ((row&7)<<4);
      *(f16*)(scb + byte) = (f16)acc[rr];
    }
  }
  __syncthreads();

  #pragma unroll
  for (int rr=0;rr<4;rr++) {
    int row = rr*4 + w;                       // wave w owns rows {w, w+4, w+8, w+12}
    int l_glob = ltile*16 + row;
    const float* brow = bias + ((size_t)b*1024 + l_glob)*1024;
    float*       orow = out  + ((size_t)b*1024 + l_glob)*1024;
    const int swz = (row&7)<<4;
    float v[16];
    float mx = -1e30f;
    #pragma unroll
    for (int it=0; it<2; ++it) {
      int cb = it*1024 + lane*16;                 // logical byte offset in row
      f16x8 s8 = *(const f16x8*)(scb + ((row*2048 + cb) ^ swz));
      int col = it*512 + lane*8;
      f32x4 b4a = *(const f32x4*)(brow + col);
      f32x4 b4b = *(const f32x4*)(brow + col + 4);
      #pragma unroll
      for (int j=0;j<4;j++) v[it*8+j]   = (float)s8[j]   + b4a[j];
      #pragma unroll
      for (int j=0;j<4;j++) v[it*8+4+j] = (float)s8[4+j] + b4b[j];
    }
    #pragma unroll
    for (int j=0;j<16;j++) mx = fmaxf(mx, v[j]);
    #pragma unroll
    for (int off=32; off>0; off>>=1) mx = fmaxf(mx, __shfl_xor(mx, off, 64));
    float sum = 0.f;
    #pragma unroll
    for (int j=0;j<16;j++) { v[j] = __expf(v[j]-mx); sum += v[j]; }
    #pragma unroll
    for (int off=32; off>0; off>>=1) sum += __shfl_xor(sum, off, 64);
    float inv = 1.0f / sum;
    #pragma unroll
    for (int it=0; it<2; ++it) {
      int col = it*512 + lane*8;
      f32x4 o4a = { v[it*8+0]*inv, v[it*8+1]*inv, v[it*8+2]*inv, v[it*8+3]*inv };
      f32x4 o4b = { v[it*8+4]*inv, v[it*8+5]*inv, v[it*8+6]*inv, v[it*8+7]*inv };
      *(f32x4*)(orow + col)     = o4a;
      *(f32x4*)(orow + col + 4) = o4b;
    }
  }
}

// ---------------------------------------------------------------------------
// Workspace layout (68 MB total):
//   qbf 16 MB | kbf 16 MB | wq 2 MB | wk 2 MB | Qh 16 MB | Kh 16 MB
// ---------------------------------------------------------------------------
extern "C" void kernel_launch(void* const* d_in, const int* in_sizes, int n_in,
                              void* d_out, int out_size, void* d_ws, size_t ws_size,
                              hipStream_t stream) {
  const float* query = (const float*)d_in[0];
  const float* key   = (const float*)d_in[1];
  const float* w     = (const float*)d_in[2];
  const float* bias  = (const float*)d_in[3];
  const float* abias = (const float*)d_in[4];
  float* out = (float*)d_out;

  char* ws = (char*)d_ws;
  const size_t QKB = (size_t)M_ROWS*E_DIM*2;  // 16 MB
  const size_t WB  = (size_t)E_DIM*E_DIM*2;   // 2 MB
  u16* qbf = (u16*)ws;  ws += QKB;
  u16* kbf = (u16*)ws;  ws += QKB;
  u16* wq  = (u16*)ws;  ws += WB;
  u16* wk  = (u16*)ws;  ws += WB;
  u16* Qh  = (u16*)ws;  ws += QKB;   // head-major [bh][l][d]
  u16* Kh  = (u16*)ws;  ws += QKB;   // head-major [bh][s][d]

  hipLaunchKernelGGL(convert_kernel, dim3(2048), dim3(256), 0, stream,
                     query, key, w, qbf, kbf, wq, wk);
  hipLaunchKernelGGL(proj_gemm, dim3(64, 8), dim3(256), 0, stream,
                     qbf, wq, bias, 0.125f, Qh);
  hipLaunchKernelGGL(proj_gemm, dim3(64, 8), dim3(256), 0, stream,
                     kbf, wk, bias + 1024, 1.0f, Kh);
  hipLaunchKernelGGL(attn_softmax, dim3(64, 128), dim3(256), 0, stream,
                     Qh, Kh, abias, out);
}